// Round 1
// baseline (251.776 us; speedup 1.0000x reference)
//
#include <hip/hip_runtime.h>
#include <cstdint>
#include <cstddef>

typedef _Float16 half_t;
typedef _Float16 half8 __attribute__((ext_vector_type(8)));
typedef float floatx4 __attribute__((ext_vector_type(4)));

#define E_ 8
#define D_ 512
#define H_ 2048
#define NTOK 1024
#define NP 2048          // NTOK * top_k
#define TM 64
#define MAX_TILES 40     // floor(2048/64) + 8 experts

__device__ __forceinline__ float gelu_f(float x) {
    return 0.5f * x * (1.0f + erff(x * 0.7071067811865476f));
}

// ---------------- init: zero counters ----------------
__global__ void init_kernel(int* cnt, int* cursor) {
    int i = threadIdx.x;
    if (i < E_) { cnt[i] = 0; cursor[i] = 0; }
}

// ---------------- gate: logits, top-2, softmax, counts ----------------
__global__ __launch_bounds__(64) void gate_kernel(
        const float* __restrict__ inp, const float* __restrict__ gate_w,
        const float* __restrict__ gate_b, float* __restrict__ score,
        int* __restrict__ idx, int* __restrict__ cnt) {
    int n = blockIdx.x;
    int lane = threadIdx.x;
    const floatx4* xr = (const floatx4*)(inp + (size_t)n * D_);
    floatx4 x0 = xr[lane * 2], x1 = xr[lane * 2 + 1];
    float l[E_];
    #pragma unroll
    for (int e = 0; e < E_; e++) {
        const floatx4* gr = (const floatx4*)(gate_w + (size_t)e * D_);
        floatx4 g0 = gr[lane * 2], g1 = gr[lane * 2 + 1];
        float p = x0[0]*g0[0] + x0[1]*g0[1] + x0[2]*g0[2] + x0[3]*g0[3]
                + x1[0]*g1[0] + x1[1]*g1[1] + x1[2]*g1[2] + x1[3]*g1[3];
        #pragma unroll
        for (int m = 1; m < 64; m <<= 1) p += __shfl_xor(p, m);
        l[e] = p + gate_b[e];
    }
    if (lane == 0) {
        int e0 = 0; float v0 = l[0];
        #pragma unroll
        for (int e = 1; e < E_; e++) if (l[e] > v0) { v0 = l[e]; e0 = e; }
        int e1 = -1; float v1 = -3.4e38f;
        #pragma unroll
        for (int e = 0; e < E_; e++) if (e != e0 && l[e] > v1) { v1 = l[e]; e1 = e; }
        float s1 = expf(v1 - v0);
        float den = 1.0f + s1;
        score[2 * n]     = 1.0f / den;
        score[2 * n + 1] = s1 / den;
        idx[2 * n]     = e0;
        idx[2 * n + 1] = e1;
        atomicAdd(&cnt[e0], 1);
        atomicAdd(&cnt[e1], 1);
    }
}

// ---------------- plan: offsets + tile table (1 thread) ----------------
__global__ void plan_kernel(const int* __restrict__ cnt, int* __restrict__ off,
                            int* __restrict__ tile_e, int* __restrict__ tile_row0,
                            int* __restrict__ tile_cnt, int* __restrict__ ntiles) {
    if (threadIdx.x != 0 || blockIdx.x != 0) return;
    int o = 0;
    for (int e = 0; e < E_; e++) { off[e] = o; o += cnt[e]; }
    off[E_] = o;
    int t = 0;
    for (int e = 0; e < E_; e++) {
        int c = cnt[e];
        int nt = (c + TM - 1) / TM;
        for (int i = 0; i < nt; i++) {
            tile_e[t] = e;
            tile_row0[t] = off[e] + i * TM;
            int rem = c - i * TM;
            tile_cnt[t] = rem < TM ? rem : TM;
            t++;
        }
    }
    ntiles[0] = t;
}

// ---------------- scatter+gather: assign positions, copy rows to f16 ----------------
__global__ __launch_bounds__(64) void scatter_kernel(
        const float* __restrict__ inp, const int* __restrict__ idx,
        const int* __restrict__ off, int* __restrict__ cursor,
        int* __restrict__ pos_of_pair, half_t* __restrict__ Xg) {
    int p = blockIdx.x, lane = threadIdx.x;
    int e = idx[p];
    int pos = 0;
    if (lane == 0) {
        pos = off[e] + atomicAdd(&cursor[e], 1);
        pos_of_pair[p] = pos;
    }
    pos = __shfl(pos, 0);
    int n = p >> 1;
    const floatx4* src = (const floatx4*)(inp + (size_t)n * D_);
    floatx4 f0 = src[lane * 2], f1 = src[lane * 2 + 1];
    half8 h = { (half_t)f0[0], (half_t)f0[1], (half_t)f0[2], (half_t)f0[3],
                (half_t)f1[0], (half_t)f1[1], (half_t)f1[2], (half_t)f1[3] };
    *(half8*)(Xg + (size_t)pos * D_ + lane * 8) = h;
}

// ---------------- fp32 -> f16 weight conversion ----------------
__global__ __launch_bounds__(256) void cvt_kernel(
        const float* __restrict__ src, half_t* __restrict__ dst, int n8) {
    int i = blockIdx.x * blockDim.x + threadIdx.x;
    if (i >= n8) return;
    const floatx4* s = (const floatx4*)src + (size_t)i * 2;
    floatx4 f0 = s[0], f1 = s[1];
    half8 h = { (half_t)f0[0], (half_t)f0[1], (half_t)f0[2], (half_t)f0[3],
                (half_t)f1[0], (half_t)f1[1], (half_t)f1[2], (half_t)f1[3] };
    *(half8*)(dst + (size_t)i * 8) = h;
}

// ---------------- GEMM1: Y1 = gelu(Xg @ W1[e]^T + b1[e]) ----------------
// block tile 64x128, 4 waves each 32x64 (2x4 fragments of 16x16), K=512
__global__ __launch_bounds__(256) void gemm1_kernel(
        const half_t* __restrict__ Xg, const half_t* __restrict__ W1h,
        const float* __restrict__ b1,
        const int* __restrict__ tile_e, const int* __restrict__ tile_row0,
        const int* __restrict__ tile_cnt, const int* __restrict__ ntiles,
        half_t* __restrict__ Y1) {
    int t = blockIdx.x;
    if (t >= ntiles[0]) return;
    int e = tile_e[t], row0 = tile_row0[t], cnt = tile_cnt[t];
    int colbase = blockIdx.y * 128;
    int wave = threadIdx.x >> 6, lane = threadIdx.x & 63;
    int quad = lane >> 4, l16 = lane & 15;
    int mbase = (wave & 1) * 32, nbase = (wave >> 1) * 64;

    const half_t* Ap[2];
    #pragma unroll
    for (int mi = 0; mi < 2; mi++) {
        int r = mbase + mi * 16 + l16;
        if (r >= cnt) r = 0;                 // clamp: results discarded on store
        Ap[mi] = Xg + (size_t)(row0 + r) * D_ + quad * 8;
    }
    const half_t* Bp[4];
    int coln[4];
    #pragma unroll
    for (int ni = 0; ni < 4; ni++) {
        int n = colbase + nbase + ni * 16 + l16;
        coln[ni] = n;
        Bp[ni] = W1h + ((size_t)e * H_ + n) * D_ + quad * 8;
    }
    floatx4 acc[2][4] = {};
    for (int k = 0; k < D_; k += 32) {
        half8 a[2], b[4];
        #pragma unroll
        for (int mi = 0; mi < 2; mi++) a[mi] = *(const half8*)(Ap[mi] + k);
        #pragma unroll
        for (int ni = 0; ni < 4; ni++) b[ni] = *(const half8*)(Bp[ni] + k);
        #pragma unroll
        for (int mi = 0; mi < 2; mi++)
            #pragma unroll
            for (int ni = 0; ni < 4; ni++)
                acc[mi][ni] = __builtin_amdgcn_mfma_f32_16x16x32_f16(a[mi], b[ni], acc[mi][ni], 0, 0, 0);
    }
    #pragma unroll
    for (int mi = 0; mi < 2; mi++) {
        #pragma unroll
        for (int r = 0; r < 4; r++) {
            int rr = mbase + mi * 16 + quad * 4 + r;
            if (rr >= cnt) continue;
            size_t rowoff = (size_t)(row0 + rr) * H_;
            #pragma unroll
            for (int ni = 0; ni < 4; ni++) {
                float v = acc[mi][ni][r] + b1[e * H_ + coln[ni]];
                Y1[rowoff + coln[ni]] = (half_t)gelu_f(v);
            }
        }
    }
}

// ---------------- GEMM2 (split-K=4): Y2p[kz] = Y1 @ W2[e]^T (no bias) ----------------
__global__ __launch_bounds__(256) void gemm2_kernel(
        const half_t* __restrict__ Y1, const half_t* __restrict__ W2h,
        const int* __restrict__ tile_e, const int* __restrict__ tile_row0,
        const int* __restrict__ tile_cnt, const int* __restrict__ ntiles,
        float* __restrict__ Y2p) {
    int t = blockIdx.x;
    if (t >= ntiles[0]) return;
    int e = tile_e[t], row0 = tile_row0[t], cnt = tile_cnt[t];
    int colbase = blockIdx.y * 128;
    int kz = blockIdx.z;
    int k0 = kz * 512;
    int wave = threadIdx.x >> 6, lane = threadIdx.x & 63;
    int quad = lane >> 4, l16 = lane & 15;
    int mbase = (wave & 1) * 32, nbase = (wave >> 1) * 64;

    const half_t* Ap[2];
    #pragma unroll
    for (int mi = 0; mi < 2; mi++) {
        int r = mbase + mi * 16 + l16;
        if (r >= cnt) r = 0;
        Ap[mi] = Y1 + (size_t)(row0 + r) * H_ + quad * 8;
    }
    const half_t* Bp[4];
    int coln[4];
    #pragma unroll
    for (int ni = 0; ni < 4; ni++) {
        int n = colbase + nbase + ni * 16 + l16;
        coln[ni] = n;
        Bp[ni] = W2h + ((size_t)e * D_ + n) * H_ + quad * 8;
    }
    floatx4 acc[2][4] = {};
    for (int k = k0; k < k0 + 512; k += 32) {
        half8 a[2], b[4];
        #pragma unroll
        for (int mi = 0; mi < 2; mi++) a[mi] = *(const half8*)(Ap[mi] + k);
        #pragma unroll
        for (int ni = 0; ni < 4; ni++) b[ni] = *(const half8*)(Bp[ni] + k);
        #pragma unroll
        for (int mi = 0; mi < 2; mi++)
            #pragma unroll
            for (int ni = 0; ni < 4; ni++)
                acc[mi][ni] = __builtin_amdgcn_mfma_f32_16x16x32_f16(a[mi], b[ni], acc[mi][ni], 0, 0, 0);
    }
    #pragma unroll
    for (int mi = 0; mi < 2; mi++) {
        #pragma unroll
        for (int r = 0; r < 4; r++) {
            int rr = mbase + mi * 16 + quad * 4 + r;
            if (rr >= cnt) continue;
            size_t rowoff = ((size_t)kz * NP + row0 + rr) * D_;
            #pragma unroll
            for (int ni = 0; ni < 4; ni++) {
                Y2p[rowoff + coln[ni]] = acc[mi][ni][r];
            }
        }
    }
}

// ---------------- combine + bias + LayerNorm, one wave per token ----------------
__global__ __launch_bounds__(64) void final_kernel(
        const float* __restrict__ Y2p, const float* __restrict__ b2,
        const int* __restrict__ idx, const float* __restrict__ score,
        const int* __restrict__ pos_of_pair,
        const float* __restrict__ ln_w, const float* __restrict__ ln_b,
        float* __restrict__ out) {
    int n = blockIdx.x, lane = threadIdx.x;
    int p0 = pos_of_pair[2 * n], p1 = pos_of_pair[2 * n + 1];
    int e0 = idx[2 * n], e1 = idx[2 * n + 1];
    float s0 = score[2 * n], s1 = score[2 * n + 1];

    const floatx4* b2r0 = (const floatx4*)(b2 + (size_t)e0 * D_);
    const floatx4* b2r1 = (const floatx4*)(b2 + (size_t)e1 * D_);
    floatx4 a_lo = b2r0[lane * 2], a_hi = b2r0[lane * 2 + 1];
    floatx4 c_lo = b2r1[lane * 2], c_hi = b2r1[lane * 2 + 1];
    #pragma unroll
    for (int kz = 0; kz < 4; kz++) {
        const floatx4* r0 = (const floatx4*)(Y2p + ((size_t)kz * NP + p0) * D_);
        const floatx4* r1 = (const floatx4*)(Y2p + ((size_t)kz * NP + p1) * D_);
        a_lo += r0[lane * 2]; a_hi += r0[lane * 2 + 1];
        c_lo += r1[lane * 2]; c_hi += r1[lane * 2 + 1];
    }
    floatx4 y_lo = s0 * a_lo + s1 * c_lo;
    floatx4 y_hi = s0 * a_hi + s1 * c_hi;

    float s = 0.0f, q = 0.0f;
    #pragma unroll
    for (int j = 0; j < 4; j++) {
        s += y_lo[j] + y_hi[j];
        q += y_lo[j] * y_lo[j] + y_hi[j] * y_hi[j];
    }
    #pragma unroll
    for (int m = 1; m < 64; m <<= 1) {
        s += __shfl_xor(s, m);
        q += __shfl_xor(q, m);
    }
    float mean = s * (1.0f / 512.0f);
    float var = q * (1.0f / 512.0f) - mean * mean;
    float inv = 1.0f / sqrtf(var + 1e-5f);

    const floatx4* wv = (const floatx4*)ln_w;
    const floatx4* bv = (const floatx4*)ln_b;
    floatx4 o_lo = (y_lo - mean) * inv * wv[lane * 2]     + bv[lane * 2];
    floatx4 o_hi = (y_hi - mean) * inv * wv[lane * 2 + 1] + bv[lane * 2 + 1];
    floatx4* op = (floatx4*)(out + (size_t)n * D_);
    op[lane * 2] = o_lo;
    op[lane * 2 + 1] = o_hi;
}

extern "C" void kernel_launch(void* const* d_in, const int* in_sizes, int n_in,
                              void* d_out, int out_size, void* d_ws, size_t ws_size,
                              hipStream_t stream) {
    const float* inp    = (const float*)d_in[0];
    const float* gate_w = (const float*)d_in[1];
    const float* gate_b = (const float*)d_in[2];
    const float* w1     = (const float*)d_in[3];
    const float* b1     = (const float*)d_in[4];
    const float* w2     = (const float*)d_in[5];
    const float* b2     = (const float*)d_in[6];
    const float* ln_w   = (const float*)d_in[7];
    const float* ln_b   = (const float*)d_in[8];
    float* out = (float*)d_out;

    char* ws = (char*)d_ws;
    size_t o = 0;
    auto carve = [&](size_t bytes) -> char* {
        char* p = ws + o;
        o += (bytes + 255) & ~(size_t)255;
        return p;
    };
    half_t* W1h = (half_t*)carve(sizeof(half_t) * (size_t)E_ * H_ * D_);   // 16 MB
    half_t* W2h = (half_t*)carve(sizeof(half_t) * (size_t)E_ * D_ * H_);   // 16 MB
    half_t* Xg  = (half_t*)carve(sizeof(half_t) * (size_t)NP * D_);        // 2 MB
    half_t* Y1  = (half_t*)carve(sizeof(half_t) * (size_t)NP * H_);        // 8 MB
    float*  Y2p = (float*)carve(sizeof(float) * 4 * (size_t)NP * D_);      // 16 MB
    float*  score = (float*)carve(sizeof(float) * NP);
    int* idx         = (int*)carve(sizeof(int) * NP);
    int* pos_of_pair = (int*)carve(sizeof(int) * NP);
    int* cnt         = (int*)carve(sizeof(int) * E_);
    int* cursor      = (int*)carve(sizeof(int) * E_);
    int* offs        = (int*)carve(sizeof(int) * (E_ + 1));
    int* tile_e      = (int*)carve(sizeof(int) * MAX_TILES);
    int* tile_row0   = (int*)carve(sizeof(int) * MAX_TILES);
    int* tile_cnt    = (int*)carve(sizeof(int) * MAX_TILES);
    int* ntiles      = (int*)carve(sizeof(int) * 1);

    init_kernel<<<1, 64, 0, stream>>>(cnt, cursor);
    gate_kernel<<<NTOK, 64, 0, stream>>>(inp, gate_w, gate_b, score, idx, cnt);
    plan_kernel<<<1, 1, 0, stream>>>(cnt, offs, tile_e, tile_row0, tile_cnt, ntiles);
    scatter_kernel<<<NP, 64, 0, stream>>>(inp, idx, offs, cursor, pos_of_pair, Xg);
    cvt_kernel<<<4096, 256, 0, stream>>>(w1, W1h, E_ * H_ * D_ / 8);
    cvt_kernel<<<4096, 256, 0, stream>>>(w2, W2h, E_ * D_ * H_ / 8);
    gemm1_kernel<<<dim3(MAX_TILES, H_ / 128), 256, 0, stream>>>(
        Xg, W1h, b1, tile_e, tile_row0, tile_cnt, ntiles, Y1);
    gemm2_kernel<<<dim3(MAX_TILES, D_ / 128, 4), 256, 0, stream>>>(
        Y1, W2h, tile_e, tile_row0, tile_cnt, ntiles, Y2p);
    final_kernel<<<NTOK, 64, 0, stream>>>(Y2p, b2, idx, score, pos_of_pair, ln_w, ln_b, out);
}

// Round 2
// 170.127 us; speedup vs baseline: 1.4799x; 1.4799x over previous
//
#include <hip/hip_runtime.h>
#include <cstdint>
#include <cstddef>

typedef _Float16 half_t;
typedef _Float16 half8 __attribute__((ext_vector_type(8)));
typedef float floatx4 __attribute__((ext_vector_type(4)));

#define E_ 8
#define D_ 512
#define H_ 2048
#define NTOK 1024
#define NP 2048          // NTOK * top_k
#define TM 128           // GEMM M-tile
#define MAX_TILES 24     // 2048/128 + 8 experts

__device__ __forceinline__ float gelu_f(float x) {
    return 0.5f * x * (1.0f + erff(x * 0.7071067811865476f));
}

// async global->LDS, 16 bytes per lane; LDS dest is wave-uniform base + lane*16
__device__ __forceinline__ void gload_lds16(const half_t* g, half_t* l) {
    __builtin_amdgcn_global_load_lds(
        (__attribute__((address_space(1))) void*)(g),
        (__attribute__((address_space(3))) void*)(l),
        16, 0, 0);
}

// ---------------- gate: logits only (no atomics) ----------------
__global__ __launch_bounds__(256) void gate_kernel(
        const float* __restrict__ inp, const float* __restrict__ gate_w,
        const float* __restrict__ gate_b, float* __restrict__ logits) {
    int n = blockIdx.x * 4 + (threadIdx.x >> 6);
    int lane = threadIdx.x & 63;
    const floatx4* xr = (const floatx4*)(inp + (size_t)n * D_);
    floatx4 x0 = xr[lane * 2], x1 = xr[lane * 2 + 1];
    #pragma unroll
    for (int e = 0; e < E_; e++) {
        const floatx4* gr = (const floatx4*)(gate_w + (size_t)e * D_);
        floatx4 g0 = gr[lane * 2], g1 = gr[lane * 2 + 1];
        float p = x0[0]*g0[0] + x0[1]*g0[1] + x0[2]*g0[2] + x0[3]*g0[3]
                + x1[0]*g1[0] + x1[1]*g1[1] + x1[2]*g1[2] + x1[3]*g1[3];
        #pragma unroll
        for (int m = 1; m < 64; m <<= 1) p += __shfl_xor(p, m);
        if (lane == 0) logits[(size_t)n * E_ + e] = p + gate_b[e];
    }
}

// ---------------- plan: single block does top2/softmax/hist/offsets/tiles ----------------
__global__ __launch_bounds__(256) void plan_kernel(
        const float* __restrict__ logits, float* __restrict__ score,
        int* __restrict__ idx, int* __restrict__ pos_of_pair,
        int* __restrict__ tile_e, int* __restrict__ tile_row0,
        int* __restrict__ tile_cnt, int* __restrict__ ntiles) {
    __shared__ int cnt_s[E_], off_s[E_ + 1], cur_s[E_];
    int tid = threadIdx.x;
    if (tid < E_) { cnt_s[tid] = 0; cur_s[tid] = 0; }
    __syncthreads();
    int my_e[4][2];
    #pragma unroll
    for (int i = 0; i < 4; i++) {
        int n = tid + i * 256;
        float l[E_];
        #pragma unroll
        for (int e = 0; e < E_; e++) l[e] = logits[(size_t)n * E_ + e];
        int e0 = 0; float v0 = l[0];
        #pragma unroll
        for (int e = 1; e < E_; e++) if (l[e] > v0) { v0 = l[e]; e0 = e; }
        int e1 = -1; float v1 = -3.4e38f;
        #pragma unroll
        for (int e = 0; e < E_; e++) if (e != e0 && l[e] > v1) { v1 = l[e]; e1 = e; }
        float s1 = expf(v1 - v0);
        float den = 1.0f + s1;
        score[2 * n]     = 1.0f / den;
        score[2 * n + 1] = s1 / den;
        idx[2 * n]     = e0;
        idx[2 * n + 1] = e1;
        atomicAdd(&cnt_s[e0], 1);
        atomicAdd(&cnt_s[e1], 1);
        my_e[i][0] = e0; my_e[i][1] = e1;
    }
    __syncthreads();
    if (tid == 0) {
        int o = 0;
        #pragma unroll
        for (int e = 0; e < E_; e++) { off_s[e] = o; o += cnt_s[e]; }
        off_s[E_] = o;
        int t = 0;
        for (int e = 0; e < E_; e++) {
            int c = cnt_s[e];
            int nt = (c + TM - 1) / TM;
            for (int i = 0; i < nt; i++) {
                tile_e[t] = e;
                tile_row0[t] = off_s[e] + i * TM;
                int rem = c - i * TM;
                tile_cnt[t] = rem < TM ? rem : TM;
                t++;
            }
        }
        ntiles[0] = t;
    }
    __syncthreads();
    #pragma unroll
    for (int i = 0; i < 4; i++) {
        #pragma unroll
        for (int k = 0; k < 2; k++) {
            int p = (tid + i * 256) * 2 + k;
            int e = my_e[i][k];
            int r = atomicAdd(&cur_s[e], 1);
            pos_of_pair[p] = off_s[e] + r;
        }
    }
}

// ---------------- scatter: copy token rows to f16 at grouped positions ----------------
__global__ __launch_bounds__(256) void scatter_kernel(
        const float* __restrict__ inp, const int* __restrict__ pos_of_pair,
        half_t* __restrict__ Xg) {
    int p = blockIdx.x * 4 + (threadIdx.x >> 6);
    int lane = threadIdx.x & 63;
    int pos = pos_of_pair[p];
    int n = p >> 1;
    const floatx4* src = (const floatx4*)(inp + (size_t)n * D_);
    floatx4 f0 = src[lane * 2], f1 = src[lane * 2 + 1];
    half8 h = { (half_t)f0[0], (half_t)f0[1], (half_t)f0[2], (half_t)f0[3],
                (half_t)f1[0], (half_t)f1[1], (half_t)f1[2], (half_t)f1[3] };
    *(half8*)(Xg + (size_t)pos * D_ + lane * 8) = h;
}

// ---------------- fp32 -> f16 weight conversion (both weights, one launch) ----------------
__global__ __launch_bounds__(256) void cvt_kernel(
        const float* __restrict__ w1, const float* __restrict__ w2,
        half_t* __restrict__ W1h, half_t* __restrict__ W2h) {
    const int n8 = E_ * H_ * D_ / 8;   // per-tensor 8-element groups
    int i = blockIdx.x * 256 + threadIdx.x;
    const float* src; half_t* dst; int j;
    if (i < n8) { src = w1; dst = W1h; j = i; }
    else        { src = w2; dst = W2h; j = i - n8; }
    const floatx4* s = (const floatx4*)src + (size_t)j * 2;
    floatx4 f0 = s[0], f1 = s[1];
    half8 h = { (half_t)f0[0], (half_t)f0[1], (half_t)f0[2], (half_t)f0[3],
                (half_t)f1[0], (half_t)f1[1], (half_t)f1[2], (half_t)f1[3] };
    *(half8*)(dst + (size_t)j * 8) = h;
}

// ---------------- GEMM1: Y1 = gelu(Xg @ W1[e]^T + b1[e]) ----------------
// 128x128 tile, BK=32, LDS staged via global_load_lds, 4 waves of 64x64
__global__ __launch_bounds__(256) void gemm1_kernel(
        const half_t* __restrict__ Xg, const half_t* __restrict__ W1h,
        const float* __restrict__ b1,
        const int* __restrict__ tile_e, const int* __restrict__ tile_row0,
        const int* __restrict__ tile_cnt, const int* __restrict__ ntiles,
        half_t* __restrict__ Y1) {
    __shared__ half_t As[TM * 32];    // 8 KB
    __shared__ half_t Bs[128 * 32];   // 8 KB
    int t = blockIdx.x;
    if (t >= ntiles[0]) return;
    int e = tile_e[t], row0 = tile_row0[t], cnt = tile_cnt[t];
    int colbase = blockIdx.y * 128;
    int tid = threadIdx.x;
    int wave = tid >> 6, lane = tid & 63;
    int quad = lane >> 4, l16 = lane & 15;
    int wm = (wave & 1) * 64, wn = (wave >> 1) * 64;

    // staging addresses: segment s covers row s>>2, cols (s&3)*8 .. +8
    int acol = (tid & 3) * 8;
    const half_t* Ag0 = Xg + (size_t)(row0 + (tid >> 2)) * D_ + acol;
    const half_t* Ag1 = Ag0 + 64 * D_;
    const half_t* Bg0 = W1h + ((size_t)e * H_ + colbase + (tid >> 2)) * D_ + acol;
    const half_t* Bg1 = Bg0 + 64 * D_;
    half_t* la0 = As + tid * 8;
    half_t* la1 = As + (tid + 256) * 8;
    half_t* lb0 = Bs + tid * 8;
    half_t* lb1 = Bs + (tid + 256) * 8;

    floatx4 acc[4][4] = {};
    for (int k0 = 0; k0 < D_; k0 += 32) {
        __syncthreads();
        gload_lds16(Ag0 + k0, la0);
        gload_lds16(Ag1 + k0, la1);
        gload_lds16(Bg0 + k0, lb0);
        gload_lds16(Bg1 + k0, lb1);
        __syncthreads();
        half8 a[4], b[4];
        #pragma unroll
        for (int mi = 0; mi < 4; mi++)
            a[mi] = *(const half8*)(As + (wm + mi * 16 + l16) * 32 + quad * 8);
        #pragma unroll
        for (int ni = 0; ni < 4; ni++)
            b[ni] = *(const half8*)(Bs + (wn + ni * 16 + l16) * 32 + quad * 8);
        #pragma unroll
        for (int mi = 0; mi < 4; mi++)
            #pragma unroll
            for (int ni = 0; ni < 4; ni++)
                acc[mi][ni] = __builtin_amdgcn_mfma_f32_16x16x32_f16(a[mi], b[ni], acc[mi][ni], 0, 0, 0);
    }
    float bias[4];
    #pragma unroll
    for (int ni = 0; ni < 4; ni++)
        bias[ni] = b1[(size_t)e * H_ + colbase + wn + ni * 16 + l16];
    #pragma unroll
    for (int mi = 0; mi < 4; mi++) {
        #pragma unroll
        for (int r = 0; r < 4; r++) {
            int rr = wm + mi * 16 + quad * 4 + r;
            if (rr >= cnt) continue;
            size_t rowoff = (size_t)(row0 + rr) * H_;
            #pragma unroll
            for (int ni = 0; ni < 4; ni++) {
                float v = acc[mi][ni][r] + bias[ni];
                Y1[rowoff + colbase + wn + ni * 16 + l16] = (half_t)gelu_f(v);
            }
        }
    }
}

// ---------------- GEMM2 (split-K=4): Y2p[kz] = Y1 @ W2[e]^T ----------------
__global__ __launch_bounds__(256) void gemm2_kernel(
        const half_t* __restrict__ Y1, const half_t* __restrict__ W2h,
        const int* __restrict__ tile_e, const int* __restrict__ tile_row0,
        const int* __restrict__ tile_cnt, const int* __restrict__ ntiles,
        float* __restrict__ Y2p) {
    __shared__ half_t As[TM * 32];
    __shared__ half_t Bs[128 * 32];
    int t = blockIdx.x;
    if (t >= ntiles[0]) return;
    int e = tile_e[t], row0 = tile_row0[t], cnt = tile_cnt[t];
    int colbase = blockIdx.y * 128;
    int kz = blockIdx.z;
    int kzbase = kz * 512;
    int tid = threadIdx.x;
    int wave = tid >> 6, lane = tid & 63;
    int quad = lane >> 4, l16 = lane & 15;
    int wm = (wave & 1) * 64, wn = (wave >> 1) * 64;

    int acol = (tid & 3) * 8;
    const half_t* Ag0 = Y1 + (size_t)(row0 + (tid >> 2)) * H_ + kzbase + acol;
    const half_t* Ag1 = Ag0 + 64 * H_;
    const half_t* Bg0 = W2h + ((size_t)e * D_ + colbase + (tid >> 2)) * H_ + kzbase + acol;
    const half_t* Bg1 = Bg0 + 64 * H_;
    half_t* la0 = As + tid * 8;
    half_t* la1 = As + (tid + 256) * 8;
    half_t* lb0 = Bs + tid * 8;
    half_t* lb1 = Bs + (tid + 256) * 8;

    floatx4 acc[4][4] = {};
    for (int k0 = 0; k0 < 512; k0 += 32) {
        __syncthreads();
        gload_lds16(Ag0 + k0, la0);
        gload_lds16(Ag1 + k0, la1);
        gload_lds16(Bg0 + k0, lb0);
        gload_lds16(Bg1 + k0, lb1);
        __syncthreads();
        half8 a[4], b[4];
        #pragma unroll
        for (int mi = 0; mi < 4; mi++)
            a[mi] = *(const half8*)(As + (wm + mi * 16 + l16) * 32 + quad * 8);
        #pragma unroll
        for (int ni = 0; ni < 4; ni++)
            b[ni] = *(const half8*)(Bs + (wn + ni * 16 + l16) * 32 + quad * 8);
        #pragma unroll
        for (int mi = 0; mi < 4; mi++)
            #pragma unroll
            for (int ni = 0; ni < 4; ni++)
                acc[mi][ni] = __builtin_amdgcn_mfma_f32_16x16x32_f16(a[mi], b[ni], acc[mi][ni], 0, 0, 0);
    }
    #pragma unroll
    for (int mi = 0; mi < 4; mi++) {
        #pragma unroll
        for (int r = 0; r < 4; r++) {
            int rr = wm + mi * 16 + quad * 4 + r;
            if (rr >= cnt) continue;
            size_t rowoff = ((size_t)kz * NP + row0 + rr) * D_;
            #pragma unroll
            for (int ni = 0; ni < 4; ni++)
                Y2p[rowoff + colbase + wn + ni * 16 + l16] = acc[mi][ni][r];
        }
    }
}

// ---------------- combine + bias + LayerNorm, wave per token ----------------
__global__ __launch_bounds__(256) void final_kernel(
        const float* __restrict__ Y2p, const float* __restrict__ b2,
        const int* __restrict__ idx, const float* __restrict__ score,
        const int* __restrict__ pos_of_pair,
        const float* __restrict__ ln_w, const float* __restrict__ ln_b,
        float* __restrict__ out) {
    int n = blockIdx.x * 4 + (threadIdx.x >> 6);
    int lane = threadIdx.x & 63;
    int p0 = pos_of_pair[2 * n], p1 = pos_of_pair[2 * n + 1];
    int e0 = idx[2 * n], e1 = idx[2 * n + 1];
    float s0 = score[2 * n], s1 = score[2 * n + 1];

    const floatx4* b2r0 = (const floatx4*)(b2 + (size_t)e0 * D_);
    const floatx4* b2r1 = (const floatx4*)(b2 + (size_t)e1 * D_);
    floatx4 a_lo = b2r0[lane * 2], a_hi = b2r0[lane * 2 + 1];
    floatx4 c_lo = b2r1[lane * 2], c_hi = b2r1[lane * 2 + 1];
    #pragma unroll
    for (int kz = 0; kz < 4; kz++) {
        const floatx4* r0 = (const floatx4*)(Y2p + ((size_t)kz * NP + p0) * D_);
        const floatx4* r1 = (const floatx4*)(Y2p + ((size_t)kz * NP + p1) * D_);
        a_lo += r0[lane * 2]; a_hi += r0[lane * 2 + 1];
        c_lo += r1[lane * 2]; c_hi += r1[lane * 2 + 1];
    }
    floatx4 y_lo = s0 * a_lo + s1 * c_lo;
    floatx4 y_hi = s0 * a_hi + s1 * c_hi;

    float s = 0.0f, q = 0.0f;
    #pragma unroll
    for (int j = 0; j < 4; j++) {
        s += y_lo[j] + y_hi[j];
        q += y_lo[j] * y_lo[j] + y_hi[j] * y_hi[j];
    }
    #pragma unroll
    for (int m = 1; m < 64; m <<= 1) {
        s += __shfl_xor(s, m);
        q += __shfl_xor(q, m);
    }
    float mean = s * (1.0f / 512.0f);
    float var = q * (1.0f / 512.0f) - mean * mean;
    float inv = 1.0f / sqrtf(var + 1e-5f);

    const floatx4* wv = (const floatx4*)ln_w;
    const floatx4* bv = (const floatx4*)ln_b;
    floatx4 o_lo = (y_lo - mean) * inv * wv[lane * 2]     + bv[lane * 2];
    floatx4 o_hi = (y_hi - mean) * inv * wv[lane * 2 + 1] + bv[lane * 2 + 1];
    floatx4* op = (floatx4*)(out + (size_t)n * D_);
    op[lane * 2] = o_lo;
    op[lane * 2 + 1] = o_hi;
}

extern "C" void kernel_launch(void* const* d_in, const int* in_sizes, int n_in,
                              void* d_out, int out_size, void* d_ws, size_t ws_size,
                              hipStream_t stream) {
    const float* inp    = (const float*)d_in[0];
    const float* gate_w = (const float*)d_in[1];
    const float* gate_b = (const float*)d_in[2];
    const float* w1     = (const float*)d_in[3];
    const float* b1     = (const float*)d_in[4];
    const float* w2     = (const float*)d_in[5];
    const float* b2     = (const float*)d_in[6];
    const float* ln_w   = (const float*)d_in[7];
    const float* ln_b   = (const float*)d_in[8];
    float* out = (float*)d_out;

    char* ws = (char*)d_ws;
    size_t o = 0;
    auto carve = [&](size_t bytes) -> char* {
        char* p = ws + o;
        o += (bytes + 255) & ~(size_t)255;
        return p;
    };
    half_t* W1h = (half_t*)carve(sizeof(half_t) * (size_t)E_ * H_ * D_);        // 16 MB
    half_t* W2h = (half_t*)carve(sizeof(half_t) * (size_t)E_ * D_ * H_);        // 16 MB
    half_t* Xg  = (half_t*)carve(sizeof(half_t) * (size_t)(NP + TM) * D_);      // 2.1 MB (slack for tile overrun)
    half_t* Y1  = (half_t*)carve(sizeof(half_t) * (size_t)(NP + TM) * H_);      // 8.9 MB (slack)
    float*  Y2p = (float*)carve(sizeof(float) * 4 * (size_t)NP * D_);           // 16.8 MB
    float*  logits = (float*)carve(sizeof(float) * NTOK * E_);
    float*  score  = (float*)carve(sizeof(float) * NP);
    int* idx         = (int*)carve(sizeof(int) * NP);
    int* pos_of_pair = (int*)carve(sizeof(int) * NP);
    int* tile_e      = (int*)carve(sizeof(int) * MAX_TILES);
    int* tile_row0   = (int*)carve(sizeof(int) * MAX_TILES);
    int* tile_cnt    = (int*)carve(sizeof(int) * MAX_TILES);
    int* ntiles      = (int*)carve(sizeof(int) * 1);

    gate_kernel<<<NTOK / 4, 256, 0, stream>>>(inp, gate_w, gate_b, logits);
    plan_kernel<<<1, 256, 0, stream>>>(logits, score, idx, pos_of_pair,
                                       tile_e, tile_row0, tile_cnt, ntiles);
    scatter_kernel<<<NP / 4, 256, 0, stream>>>(inp, pos_of_pair, Xg);
    cvt_kernel<<<2 * E_ * H_ * D_ / 8 / 256, 256, 0, stream>>>(w1, w2, W1h, W2h);
    gemm1_kernel<<<dim3(MAX_TILES, H_ / 128), 256, 0, stream>>>(
        Xg, W1h, b1, tile_e, tile_row0, tile_cnt, ntiles, Y1);
    gemm2_kernel<<<dim3(MAX_TILES, D_ / 128, 4), 256, 0, stream>>>(
        Y1, W2h, tile_e, tile_row0, tile_cnt, ntiles, Y2p);
    final_kernel<<<NTOK / 4, 256, 0, stream>>>(Y2p, b2, idx, score, pos_of_pair, ln_w, ln_b, out);
}